// Round 12
// baseline (396.242 us; speedup 1.0000x reference)
//
#include <hip/hip_runtime.h>

// ---------------------------------------------------------------------------
// DistributionShiftGAT: 3-layer GAT on MI355X (gfx950).
// R12: agg index chain de-serialized: one coalesced 64-index load per wave +
//      shfl/readfirstlane broadcast (was: one broadcast memory load per edge).
//      L3 agg (F=128, latency-bound at 256B/edge) pipeline depth 4 -> 8.
//      GEMM = R11 wide tiles (128x256 / 256x128, 8 waves, BK=64).
//      Agg pattern wall: ~75us, FETCH = 8 XCDs x table (compulsory), fabric
//      ~3.7 TB/s invariant across R5/R6/R8/R10/R11 variants.
// ---------------------------------------------------------------------------

#define NEG_SLOPE 0.2f

typedef __attribute__((ext_vector_type(8))) short short8;
typedef __attribute__((ext_vector_type(4))) float floatx4;

static __device__ __forceinline__ unsigned short f2bf(float f) {
    unsigned u = __float_as_uint(f);
    u = u + 0x7FFFu + ((u >> 16) & 1u);      // RNE
    return (unsigned short)(u >> 16);
}
static __device__ __forceinline__ float bf2f_lo(unsigned u) {
    return __uint_as_float(u << 16);
}
static __device__ __forceinline__ float bf2f_hi(unsigned u) {
    return __uint_as_float(u & 0xFFFF0000u);
}

// async global->LDS, 16B per lane; LDS fills base + lane*16 (wave-uniform base)
static __device__ __forceinline__ void async_copy16(const void* g, void* l) {
    __builtin_amdgcn_global_load_lds(
        (const __attribute__((address_space(1))) unsigned int*)g,
        (__attribute__((address_space(3))) unsigned int*)l, 16, 0, 0);
}

// ---------------- fused prep (x cast + W transposes) + edge histogram -------
// cursor must be zeroed (hipMemsetAsync) before this kernel.

__global__ __launch_bounds__(256)
void prep_hist_kernel(const float* __restrict__ x, unsigned short* __restrict__ x_bf,
                      const float* __restrict__ W1, unsigned short* __restrict__ W1T,
                      const float* __restrict__ W2, unsigned short* __restrict__ W2T,
                      const float* __restrict__ W3, unsigned short* __restrict__ W3T,
                      const int* __restrict__ ei, int* cursor, int n4, int E) {
    int i = blockIdx.x * 256 + threadIdx.x;
    if (i < n4) {
        float4 v = ((const float4*)x)[i];
        ushort4 o;
        o.x = f2bf(v.x); o.y = f2bf(v.y); o.z = f2bf(v.z); o.w = f2bf(v.w);
        ((ushort4*)x_bf)[i] = o;
        return;
    }
    int j = i - n4;
    if (j < 256 * 512) {                       // W1 [256,512] -> W1T [512,256]
        int k = j >> 9, n = j & 511;
        W1T[(size_t)n * 256 + k] = f2bf(W1[j]);
        return;
    }
    j -= 256 * 512;
    if (j < 512 * 512) {                       // W2 [512,512] -> W2T [512,512]
        int k = j >> 9, n = j & 511;
        W2T[(size_t)n * 512 + k] = f2bf(W2[j]);
        return;
    }
    j -= 512 * 512;
    if (j < 512 * 128) {                       // W3 [512,128] -> W3T [128,512]
        int k = j >> 7, n = j & 127;
        W3T[(size_t)n * 512 + k] = f2bf(W3[j]);
        return;
    }
    j -= 512 * 128;
    if (j < E) atomicAdd(&cursor[ei[E + j]], 1);   // histogram of dst
}

// ---------------- CSR scan (self-loops folded: row_ptr[i]=edge_prefix+i) ----

__global__ __launch_bounds__(1024)
void scan_bsum_kernel(const int* __restrict__ cursor, int* __restrict__ bsum, int N) {
    __shared__ int wsum[16];
    int tid = threadIdx.x, lane = tid & 63, w = tid >> 6;
    int i = blockIdx.x * 1024 + tid;
    int v = (i < N) ? cursor[i] : 0;
    #pragma unroll
    for (int off = 32; off; off >>= 1) v += __shfl_xor(v, off, 64);
    if (lane == 0) wsum[w] = v;
    __syncthreads();
    if (tid == 0) {
        int t = 0;
        #pragma unroll
        for (int k = 0; k < 16; ++k) t += wsum[k];
        bsum[blockIdx.x] = t;
    }
}

__global__ __launch_bounds__(1024)
void scan_final_kernel(int* __restrict__ cursor, const int* __restrict__ bsum,
                       int* __restrict__ row_ptr, int N, int NB) {
    __shared__ int wsum[16];
    __shared__ int boff_sh;
    int tid = threadIdx.x, lane = tid & 63, w = tid >> 6;
    if (w == 0) {
        int bv = (lane < NB) ? bsum[lane] : 0;
        int bx = bv;
        #pragma unroll
        for (int off = 1; off < 64; off <<= 1) {
            int t = __shfl_up(bx, off, 64);
            if (lane >= off) bx += t;
        }
        if (lane == blockIdx.x) boff_sh = bx - bv;       // exclusive prefix
        if (blockIdx.x == 0 && lane == 63) row_ptr[N] = bx + N;  // +N self-loops
    }
    int i = blockIdx.x * 1024 + tid;
    int v = (i < N) ? cursor[i] : 0;
    int x = v;
    #pragma unroll
    for (int off = 1; off < 64; off <<= 1) {
        int t = __shfl_up(x, off, 64);
        if (lane >= off) x += t;
    }
    if (lane == 63) wsum[w] = x;
    __syncthreads();
    if (w == 0 && lane < 16) {
        int y = wsum[lane];
        #pragma unroll
        for (int off = 1; off < 16; off <<= 1) {
            int t = __shfl_up(y, off, 64);
            if (lane >= off) y += t;
        }
        wsum[lane] = y;
    }
    __syncthreads();
    int woff = (w == 0) ? 0 : wsum[w - 1];
    int ex = boff_sh + woff + x - v + i;     // + i = self-loop slots
    if (i < N) { row_ptr[i] = ex; cursor[i] = ex; }
}

__global__ __launch_bounds__(256)
void scatter_kernel(const int* __restrict__ ei, int* cursor,
                    int* __restrict__ csr_src, int E, int N) {
    int i = blockIdx.x * 256 + threadIdx.x;
    if (i < E) {
        int s = ei[i], d = ei[E + i];
        int pos = atomicAdd(&cursor[d], 1);
        csr_src[pos] = s;
    } else if (i < E + N) {
        int n = i - E;
        int pos = atomicAdd(&cursor[n], 1);
        csr_src[pos] = n;                // self loop
    }
}

// ---------------- bf16 MFMA GEMM + fused attention dots (R11 version) -------
// C[M,Nn]bf16 = A[M,K]bf16 @ BT[Nn,K]^T. TMxTN tile, BK=64, 8 waves (512 thr),
// 64x64 wave tiles. A+B staged into one 48KB LDS buffer via global_load_lds;
// phys seg = seg ^ (row&7) keeps staging and b128 frag reads bank-minimal.
// Epilogue computes a_src/a_dst for the TN/128 heads this block covers.
// [History: R7 LDS-free regressed; R10 BK=64 +7us; R11 wide tiles +20us]

template<int TM, int TN>
__global__ __launch_bounds__(512)
void mfma_gemm_kernel(const unsigned short* __restrict__ A,
                      const unsigned short* __restrict__ BT,
                      unsigned short* __restrict__ C,
                      const float* __restrict__ att_src,
                      const float* __restrict__ att_dst,
                      float* __restrict__ a_srcO, float* __restrict__ a_dstO,
                      int H, int M, int Nn, int K) {
    constexpr int NH = TN / 128;               // heads per block
    __shared__ unsigned short buf[(TM + TN) * 64];    // 48 KB
    __shared__ float psum[TN / 64][TM];
    __shared__ float pdsum[TN / 64][TM];
    const int tid = threadIdx.x;
    const int m0 = blockIdx.y * TM;
    const int n0 = blockIdx.x * TN;
    const int head_base = blockIdx.x * NH;
    const int lane = tid & 63, wave = tid >> 6;        // wave 0..7
    const int wm = (wave & (TM / 64 - 1)) * 64;
    const int wn = (wave / (TM / 64)) * 64;
    const int quad = lane >> 4, rr = lane & 15;

    // staging: 8 waves x 6 insts x 8 rows = 384 rows (TM A-rows + TN B-rows)
    const int srow = lane >> 3;                // row within 8-row group
    const int sseg = (lane & 7) ^ srow;        // logical 8-elem seg to fetch
    const unsigned short* gptr[6];
    unsigned short* lptr[6];
    #pragma unroll
    for (int j = 0; j < 6; ++j) {
        int base_row = wave * 48 + j * 8;      // multiple of 8; A/B uniform
        lptr[j] = buf + base_row * 64;
        if (base_row < TM) {
            int gr = min(m0 + base_row + srow, M - 1);
            gptr[j] = A + (size_t)gr * K;
        } else {
            int gr = n0 + (base_row - TM) + srow;
            gptr[j] = BT + (size_t)gr * K;
        }
    }

    floatx4 acc[4][4] = {};

    for (int k0 = 0; k0 < K; k0 += 64) {
        #pragma unroll
        for (int j = 0; j < 6; ++j)
            async_copy16(gptr[j] + k0 + sseg * 8, lptr[j]);
        __syncthreads();

        #pragma unroll
        for (int k32 = 0; k32 < 2; ++k32) {
            short8 af[4], bf[4];
            #pragma unroll
            for (int mi = 0; mi < 4; ++mi) {
                int row = wm + mi * 16 + rr;
                int phys = (k32 * 4 + quad) ^ (rr & 7);
                af[mi] = *(const short8*)(buf + row * 64 + phys * 8);
            }
            #pragma unroll
            for (int ni = 0; ni < 4; ++ni) {
                int row = TM + wn + ni * 16 + rr;
                int phys = (k32 * 4 + quad) ^ (rr & 7);
                bf[ni] = *(const short8*)(buf + row * 64 + phys * 8);
            }
            #pragma unroll
            for (int mi = 0; mi < 4; ++mi)
                #pragma unroll
                for (int ni = 0; ni < 4; ++ni)
                    acc[mi][ni] = __builtin_amdgcn_mfma_f32_16x16x32_bf16(
                        af[mi], bf[ni], acc[mi][ni], 0, 0, 0);
        }
        __syncthreads();
    }

    // ---- h store (bf16), C/D layout: col=lane&15, row=quad*4+reg ----
    #pragma unroll
    for (int mi = 0; mi < 4; ++mi) {
        #pragma unroll
        for (int ni = 0; ni < 4; ++ni) {
            int col = n0 + wn + ni * 16 + rr;
            #pragma unroll
            for (int r = 0; r < 4; ++r) {
                int row = m0 + wm + mi * 16 + quad * 4 + r;
                if (row < M) C[(size_t)row * Nn + col] = f2bf(acc[mi][ni][r]);
            }
        }
    }

    // ---- fused attention dots (per covered head) ----
    float ats[4], atd[4];
    #pragma unroll
    for (int ni = 0; ni < 4; ++ni) {
        int cc = wn + ni * 16;                  // col within block tile
        int h = head_base + (cc >> 7);
        int c = (cc + rr) & 127;                // channel within head
        ats[ni] = att_src[h * 128 + c];
        atd[ni] = att_dst[h * 128 + c];
    }
    const int wg = wn >> 6;                     // wave column group
    #pragma unroll
    for (int mi = 0; mi < 4; ++mi) {
        #pragma unroll
        for (int r = 0; r < 4; ++r) {
            float ps = 0.f, pd = 0.f;
            #pragma unroll
            for (int ni = 0; ni < 4; ++ni) {
                ps += ats[ni] * acc[mi][ni][r];
                pd += atd[ni] * acc[mi][ni][r];
            }
            #pragma unroll
            for (int off = 1; off < 16; off <<= 1) {
                ps += __shfl_xor(ps, off, 64);
                pd += __shfl_xor(pd, off, 64);
            }
            if (rr == 0) {
                int row = wm + mi * 16 + quad * 4 + r;   // local row
                psum[wg][row] = ps;
                pdsum[wg][row] = pd;
            }
        }
    }
    __syncthreads();
    if (tid < NH * TM) {
        int h = tid / TM, r = tid % TM;
        int gr = m0 + r;
        if (gr < M) {
            a_srcO[(size_t)gr * H + head_base + h] = psum[2 * h][r] + psum[2 * h + 1][r];
            a_dstO[(size_t)gr * H + head_base + h] = pdsum[2 * h][r] + pdsum[2 * h + 1][r];
        }
    }
}

// ---------------- per-dst-node softmax + aggregation ----------------
// One WAVE per dst node. Single pass: exp(e) without max subtraction (logits
// O(1): identical ratio, fp32-safe). R12: edge indices loaded 64-at-a-time
// (one coalesced load) and broadcast via shfl+readfirstlane -- removes the
// per-edge broadcast-load dependency link. Depth-4 value pipeline (16B/lane)
// for F=512; depth-8 for F=128 (256B/edge, latency-bound). No LDS/barriers.
// Edge consumption stays in order -> sums bitwise-identical to R11.

template<int F, int H, bool RELU, bool BF16OUT>
__global__ __launch_bounds__(256)
void agg_kernel(const unsigned* __restrict__ hfeat, const float* __restrict__ a_src,
                const float* __restrict__ a_dst, const int* __restrict__ row_ptr,
                const int* __restrict__ csr_src, const float* __restrict__ bias,
                void* __restrict__ out_v, int N) {
    constexpr int UPL = F / 128;             // uints per lane: 4 or 1
    constexpr int RU = F / 2;                // uints per row
    constexpr int DEPTH = (UPL == 1) ? 8 : 4;
    const int wave = threadIdx.x >> 6, lane = threadIdx.x & 63;
    const int n = blockIdx.x * 4 + wave;
    if (n >= N) return;
    const int begin = __builtin_amdgcn_readfirstlane(row_ptr[n]);
    const int deg = __builtin_amdgcn_readfirstlane(row_ptr[n + 1]) - begin;
    const int myh = (2 * UPL * lane) / 128;
    const float adst = a_dst[n * H + myh];

    float acc[2 * UPL];
    #pragma unroll
    for (int j = 0; j < 2 * UPL; ++j) acc[j] = 0.f;
    float dacc = 0.f;

    unsigned u[DEPTH][UPL];
    float av[DEPTH];

    for (int base = 0; base < deg; base += 64) {
        const int cnt = min(64, deg - base);
        // one coalesced index load for the whole chunk
        int sv = csr_src[begin + base + min(lane, cnt - 1)];

#define LOAD(d, idx)                                                        \
    {                                                                       \
        int s_ = __builtin_amdgcn_readfirstlane(__shfl(sv, (idx), 64));     \
        if (UPL == 4) {                                                     \
            uint4 t_ = ((const uint4*)(hfeat + (size_t)s_ * RU))[lane];     \
            u[d][0] = t_.x; u[d][1] = t_.y; u[d][2] = t_.z; u[d][3] = t_.w; \
        } else {                                                            \
            u[d][0] = hfeat[(size_t)s_ * RU + lane];                        \
        }                                                                   \
        av[d] = a_src[s_ * H + myh];                                        \
    }

#define CONSUME(d)                                                          \
    {                                                                       \
        float e_ = av[d] + adst;                                            \
        e_ = e_ > 0.f ? e_ : NEG_SLOPE * e_;                                \
        float ex_ = __expf(e_);                                             \
        dacc += ex_;                                                        \
        _Pragma("unroll")                                                   \
        for (int q_ = 0; q_ < UPL; ++q_) {                                  \
            acc[2 * q_]     += ex_ * bf2f_lo(u[d][q_]);                     \
            acc[2 * q_ + 1] += ex_ * bf2f_hi(u[d][q_]);                     \
        }                                                                   \
    }

        // fill pipeline
        #pragma unroll
        for (int d = 0; d < DEPTH; ++d)
            if (d < cnt) LOAD(d, d);
        // steady state: invariant at loop top, slot d holds edge j+d
        int j = 0;
        for (; j + 2 * DEPTH <= cnt; j += DEPTH) {
            #pragma unroll
            for (int d = 0; d < DEPTH; ++d) { CONSUME(d); LOAD(d, j + DEPTH + d); }
        }
        // tail: r in [0, 2*DEPTH)
        const int r = cnt - j;
        #pragma unroll
        for (int d = 0; d < DEPTH; ++d) {
            if (d < r) {
                CONSUME(d);
                if (d + DEPTH < r) LOAD(d, j + DEPTH + d);
            }
        }
        #pragma unroll
        for (int d = 0; d < DEPTH; ++d)
            if (d + DEPTH < r) CONSUME(d);
#undef LOAD
#undef CONSUME
    }

    // epilogue: lane owns channels [2*UPL*lane, 2*UPL*lane + 2*UPL)
    float inv = 1.f / dacc;
    const int cb = 2 * UPL * lane;
    if (BF16OUT) {
        unsigned pk[UPL];
        #pragma unroll
        for (int q = 0; q < UPL; ++q) {
            float v0 = acc[2 * q] * inv + bias[cb + 2 * q];
            float v1 = acc[2 * q + 1] * inv + bias[cb + 2 * q + 1];
            if (RELU) { v0 = fmaxf(v0, 0.f); v1 = fmaxf(v1, 0.f); }
            pk[q] = (unsigned)f2bf(v0) | ((unsigned)f2bf(v1) << 16);
        }
        if (UPL == 4) {
            uint4 t; t.x = pk[0]; t.y = pk[1]; t.z = pk[2]; t.w = pk[3];
            ((uint4*)((unsigned*)out_v + (size_t)n * RU))[lane] = t;
        } else {
            ((unsigned*)out_v)[(size_t)n * RU + lane] = pk[0];
        }
    } else {
        #pragma unroll
        for (int q = 0; q < UPL; ++q) {
            float v0 = acc[2 * q] * inv + bias[cb + 2 * q];
            float v1 = acc[2 * q + 1] * inv + bias[cb + 2 * q + 1];
            if (RELU) { v0 = fmaxf(v0, 0.f); v1 = fmaxf(v1, 0.f); }
            float2 o; o.x = v0; o.y = v1;
            ((float2*)((float*)out_v + (size_t)n * F))[UPL * lane + q] = o;
        }
    }
}

// ---------------- host launch ----------------

extern "C" void kernel_launch(void* const* d_in, const int* in_sizes, int n_in,
                              void* d_out, int out_size, void* d_ws, size_t ws_size,
                              hipStream_t stream) {
    const float* x        = (const float*)d_in[0];
    const int*   ei       = (const int*)  d_in[1];
    const float* W1       = (const float*)d_in[2];
    const float* att_src1 = (const float*)d_in[3];
    const float* att_dst1 = (const float*)d_in[4];
    const float* b1       = (const float*)d_in[5];
    const float* W2       = (const float*)d_in[6];
    const float* att_src2 = (const float*)d_in[7];
    const float* att_dst2 = (const float*)d_in[8];
    const float* b2       = (const float*)d_in[9];
    const float* W3       = (const float*)d_in[10];
    const float* att_src3 = (const float*)d_in[11];
    const float* att_dst3 = (const float*)d_in[12];
    const float* b3       = (const float*)d_in[13];

    const int IN_FEATS = 256;
    const int N = in_sizes[0] / IN_FEATS;   // 30000
    const int E = in_sizes[1] / 2;          // 480000
    const int ET = E + N;
    const int NB = (N + 1023) / 1024;       // scan blocks (30)

    // workspace layout
    char* p = (char*)d_ws;
    unsigned short* h_bf    = (unsigned short*)p; p += (size_t)N * 512 * sizeof(unsigned short);
    unsigned short* act_bf  = (unsigned short*)p; p += (size_t)N * 512 * sizeof(unsigned short);
    unsigned short* x_bf    = (unsigned short*)p; p += (size_t)N * 256 * sizeof(unsigned short);
    float*          a_src   = (float*)p;          p += (size_t)N * 4 * sizeof(float);
    float*          a_dst   = (float*)p;          p += (size_t)N * 4 * sizeof(float);
    unsigned short* W1T     = (unsigned short*)p; p += (size_t)512 * 256 * sizeof(unsigned short);
    unsigned short* W2T     = (unsigned short*)p; p += (size_t)512 * 512 * sizeof(unsigned short);
    unsigned short* W3T     = (unsigned short*)p; p += (size_t)128 * 512 * sizeof(unsigned short);
    int*            row_ptr = (int*)p;            p += ((size_t)N + 16) * sizeof(int);
    int*            cursor  = (int*)p;            p += ((size_t)N + 16) * sizeof(int);
    int*            bsum    = (int*)p;            p += 64 * sizeof(int);
    int*            csr_src = (int*)p;            p += (size_t)ET * sizeof(int);

    // ---- prep (x cast + W transposes + hist) + CSR build ----
    hipMemsetAsync(cursor, 0, (size_t)N * sizeof(int), stream);
    {
        int n4 = N * 256 / 4;
        int total = n4 + 256 * 512 + 512 * 512 + 512 * 128 + E;
        prep_hist_kernel<<<(total + 255) / 256, 256, 0, stream>>>(
            x, x_bf, W1, W1T, W2, W2T, W3, W3T, ei, cursor, n4, E);
    }
    scan_bsum_kernel<<<NB, 1024, 0, stream>>>(cursor, bsum, N);
    scan_final_kernel<<<NB, 1024, 0, stream>>>(cursor, bsum, row_ptr, N, NB);
    scatter_kernel<<<(E + N + 255) / 256, 256, 0, stream>>>(ei, cursor, csr_src, E, N);

    const int MB128 = (N + 127) / 128;      // 235
    const int MB256 = (N + 255) / 256;      // 118
    const int NB4 = (N + 3) / 4;

    // ---- Layer 1: 256 -> 4x128 concat + relu (h bf16) ----
    mfma_gemm_kernel<128, 256><<<dim3(2, MB128), 512, 0, stream>>>(x_bf, W1T, h_bf, att_src1, att_dst1, a_src, a_dst, 4, N, 512, 256);
    agg_kernel<512, 4, true, true><<<NB4, 256, 0, stream>>>((const unsigned*)h_bf, a_src, a_dst, row_ptr, csr_src, b1, act_bf, N);

    // ---- Layer 2: 512 -> 4x128 concat + relu (h bf16) ----
    mfma_gemm_kernel<128, 256><<<dim3(2, MB128), 512, 0, stream>>>(act_bf, W2T, h_bf, att_src2, att_dst2, a_src, a_dst, 4, N, 512, 512);
    agg_kernel<512, 4, true, true><<<NB4, 256, 0, stream>>>((const unsigned*)h_bf, a_src, a_dst, row_ptr, csr_src, b2, act_bf, N);

    // ---- Layer 3: 512 -> 1x128 (h bf16), fp32 out, no relu ----
    mfma_gemm_kernel<256, 128><<<dim3(1, MB256), 512, 0, stream>>>(act_bf, W3T, h_bf, att_src3, att_dst3, a_src, a_dst, 1, N, 128, 512);
    agg_kernel<128, 1, false, false><<<NB4, 256, 0, stream>>>((const unsigned*)h_bf, a_src, a_dst, row_ptr, csr_src, b3, d_out, N);
}

// Round 13
// 394.570 us; speedup vs baseline: 1.0042x; 1.0042x over previous
//
#include <hip/hip_runtime.h>

// ---------------------------------------------------------------------------
// DistributionShiftGAT: 3-layer GAT on MI355X (gfx950).
// R13: = R11 (best, 388.9us) + depth-parametrized agg pipeline (8 for F=128
//      layer-3 agg, 4 for F=512). R12's shfl-index broadcast REVERTED: variable
//      __shfl = ds_bpermute -> added LDS latency into the per-edge address
//      chain (389->396 regression). Scalar broadcast loads restored.
//      Agg pattern wall (6x confirmed): ~75us, FETCH = 8 XCDs x 30.7MB table,
//      ~3.7 TB/s fabric, invariant across R5/R6/R8/R10/R11/R12 variants.
// ---------------------------------------------------------------------------

#define NEG_SLOPE 0.2f

typedef __attribute__((ext_vector_type(8))) short short8;
typedef __attribute__((ext_vector_type(4))) float floatx4;

static __device__ __forceinline__ unsigned short f2bf(float f) {
    unsigned u = __float_as_uint(f);
    u = u + 0x7FFFu + ((u >> 16) & 1u);      // RNE
    return (unsigned short)(u >> 16);
}
static __device__ __forceinline__ float bf2f_lo(unsigned u) {
    return __uint_as_float(u << 16);
}
static __device__ __forceinline__ float bf2f_hi(unsigned u) {
    return __uint_as_float(u & 0xFFFF0000u);
}

// async global->LDS, 16B per lane; LDS fills base + lane*16 (wave-uniform base)
static __device__ __forceinline__ void async_copy16(const void* g, void* l) {
    __builtin_amdgcn_global_load_lds(
        (const __attribute__((address_space(1))) unsigned int*)g,
        (__attribute__((address_space(3))) unsigned int*)l, 16, 0, 0);
}

// ---------------- fused prep (x cast + W transposes) + edge histogram -------
// cursor must be zeroed (hipMemsetAsync) before this kernel.

__global__ __launch_bounds__(256)
void prep_hist_kernel(const float* __restrict__ x, unsigned short* __restrict__ x_bf,
                      const float* __restrict__ W1, unsigned short* __restrict__ W1T,
                      const float* __restrict__ W2, unsigned short* __restrict__ W2T,
                      const float* __restrict__ W3, unsigned short* __restrict__ W3T,
                      const int* __restrict__ ei, int* cursor, int n4, int E) {
    int i = blockIdx.x * 256 + threadIdx.x;
    if (i < n4) {
        float4 v = ((const float4*)x)[i];
        ushort4 o;
        o.x = f2bf(v.x); o.y = f2bf(v.y); o.z = f2bf(v.z); o.w = f2bf(v.w);
        ((ushort4*)x_bf)[i] = o;
        return;
    }
    int j = i - n4;
    if (j < 256 * 512) {                       // W1 [256,512] -> W1T [512,256]
        int k = j >> 9, n = j & 511;
        W1T[(size_t)n * 256 + k] = f2bf(W1[j]);
        return;
    }
    j -= 256 * 512;
    if (j < 512 * 512) {                       // W2 [512,512] -> W2T [512,512]
        int k = j >> 9, n = j & 511;
        W2T[(size_t)n * 512 + k] = f2bf(W2[j]);
        return;
    }
    j -= 512 * 512;
    if (j < 512 * 128) {                       // W3 [512,128] -> W3T [128,512]
        int k = j >> 7, n = j & 127;
        W3T[(size_t)n * 512 + k] = f2bf(W3[j]);
        return;
    }
    j -= 512 * 128;
    if (j < E) atomicAdd(&cursor[ei[E + j]], 1);   // histogram of dst
}

// ---------------- CSR scan (self-loops folded: row_ptr[i]=edge_prefix+i) ----

__global__ __launch_bounds__(1024)
void scan_bsum_kernel(const int* __restrict__ cursor, int* __restrict__ bsum, int N) {
    __shared__ int wsum[16];
    int tid = threadIdx.x, lane = tid & 63, w = tid >> 6;
    int i = blockIdx.x * 1024 + tid;
    int v = (i < N) ? cursor[i] : 0;
    #pragma unroll
    for (int off = 32; off; off >>= 1) v += __shfl_xor(v, off, 64);
    if (lane == 0) wsum[w] = v;
    __syncthreads();
    if (tid == 0) {
        int t = 0;
        #pragma unroll
        for (int k = 0; k < 16; ++k) t += wsum[k];
        bsum[blockIdx.x] = t;
    }
}

__global__ __launch_bounds__(1024)
void scan_final_kernel(int* __restrict__ cursor, const int* __restrict__ bsum,
                       int* __restrict__ row_ptr, int N, int NB) {
    __shared__ int wsum[16];
    __shared__ int boff_sh;
    int tid = threadIdx.x, lane = tid & 63, w = tid >> 6;
    if (w == 0) {
        int bv = (lane < NB) ? bsum[lane] : 0;
        int bx = bv;
        #pragma unroll
        for (int off = 1; off < 64; off <<= 1) {
            int t = __shfl_up(bx, off, 64);
            if (lane >= off) bx += t;
        }
        if (lane == blockIdx.x) boff_sh = bx - bv;       // exclusive prefix
        if (blockIdx.x == 0 && lane == 63) row_ptr[N] = bx + N;  // +N self-loops
    }
    int i = blockIdx.x * 1024 + tid;
    int v = (i < N) ? cursor[i] : 0;
    int x = v;
    #pragma unroll
    for (int off = 1; off < 64; off <<= 1) {
        int t = __shfl_up(x, off, 64);
        if (lane >= off) x += t;
    }
    if (lane == 63) wsum[w] = x;
    __syncthreads();
    if (w == 0 && lane < 16) {
        int y = wsum[lane];
        #pragma unroll
        for (int off = 1; off < 16; off <<= 1) {
            int t = __shfl_up(y, off, 64);
            if (lane >= off) y += t;
        }
        wsum[lane] = y;
    }
    __syncthreads();
    int woff = (w == 0) ? 0 : wsum[w - 1];
    int ex = boff_sh + woff + x - v + i;     // + i = self-loop slots
    if (i < N) { row_ptr[i] = ex; cursor[i] = ex; }
}

__global__ __launch_bounds__(256)
void scatter_kernel(const int* __restrict__ ei, int* cursor,
                    int* __restrict__ csr_src, int E, int N) {
    int i = blockIdx.x * 256 + threadIdx.x;
    if (i < E) {
        int s = ei[i], d = ei[E + i];
        int pos = atomicAdd(&cursor[d], 1);
        csr_src[pos] = s;
    } else if (i < E + N) {
        int n = i - E;
        int pos = atomicAdd(&cursor[n], 1);
        csr_src[pos] = n;                // self loop
    }
}

// ---------------- bf16 MFMA GEMM + fused attention dots (R11 version) -------
// C[M,Nn]bf16 = A[M,K]bf16 @ BT[Nn,K]^T. TMxTN tile, BK=64, 8 waves (512 thr),
// 64x64 wave tiles. A+B staged into one 48KB LDS buffer via global_load_lds;
// phys seg = seg ^ (row&7) keeps staging and b128 frag reads bank-minimal.
// Epilogue computes a_src/a_dst for the TN/128 heads this block covers.
// [History: R7 LDS-free regressed; R10 BK=64 +7us; R11 wide tiles +20us]

template<int TM, int TN>
__global__ __launch_bounds__(512)
void mfma_gemm_kernel(const unsigned short* __restrict__ A,
                      const unsigned short* __restrict__ BT,
                      unsigned short* __restrict__ C,
                      const float* __restrict__ att_src,
                      const float* __restrict__ att_dst,
                      float* __restrict__ a_srcO, float* __restrict__ a_dstO,
                      int H, int M, int Nn, int K) {
    constexpr int NH = TN / 128;               // heads per block
    __shared__ unsigned short buf[(TM + TN) * 64];    // 48 KB
    __shared__ float psum[TN / 64][TM];
    __shared__ float pdsum[TN / 64][TM];
    const int tid = threadIdx.x;
    const int m0 = blockIdx.y * TM;
    const int n0 = blockIdx.x * TN;
    const int head_base = blockIdx.x * NH;
    const int lane = tid & 63, wave = tid >> 6;        // wave 0..7
    const int wm = (wave & (TM / 64 - 1)) * 64;
    const int wn = (wave / (TM / 64)) * 64;
    const int quad = lane >> 4, rr = lane & 15;

    // staging: 8 waves x 6 insts x 8 rows = 384 rows (TM A-rows + TN B-rows)
    const int srow = lane >> 3;                // row within 8-row group
    const int sseg = (lane & 7) ^ srow;        // logical 8-elem seg to fetch
    const unsigned short* gptr[6];
    unsigned short* lptr[6];
    #pragma unroll
    for (int j = 0; j < 6; ++j) {
        int base_row = wave * 48 + j * 8;      // multiple of 8; A/B uniform
        lptr[j] = buf + base_row * 64;
        if (base_row < TM) {
            int gr = min(m0 + base_row + srow, M - 1);
            gptr[j] = A + (size_t)gr * K;
        } else {
            int gr = n0 + (base_row - TM) + srow;
            gptr[j] = BT + (size_t)gr * K;
        }
    }

    floatx4 acc[4][4] = {};

    for (int k0 = 0; k0 < K; k0 += 64) {
        #pragma unroll
        for (int j = 0; j < 6; ++j)
            async_copy16(gptr[j] + k0 + sseg * 8, lptr[j]);
        __syncthreads();

        #pragma unroll
        for (int k32 = 0; k32 < 2; ++k32) {
            short8 af[4], bf[4];
            #pragma unroll
            for (int mi = 0; mi < 4; ++mi) {
                int row = wm + mi * 16 + rr;
                int phys = (k32 * 4 + quad) ^ (rr & 7);
                af[mi] = *(const short8*)(buf + row * 64 + phys * 8);
            }
            #pragma unroll
            for (int ni = 0; ni < 4; ++ni) {
                int row = TM + wn + ni * 16 + rr;
                int phys = (k32 * 4 + quad) ^ (rr & 7);
                bf[ni] = *(const short8*)(buf + row * 64 + phys * 8);
            }
            #pragma unroll
            for (int mi = 0; mi < 4; ++mi)
                #pragma unroll
                for (int ni = 0; ni < 4; ++ni)
                    acc[mi][ni] = __builtin_amdgcn_mfma_f32_16x16x32_bf16(
                        af[mi], bf[ni], acc[mi][ni], 0, 0, 0);
        }
        __syncthreads();
    }

    // ---- h store (bf16), C/D layout: col=lane&15, row=quad*4+reg ----
    #pragma unroll
    for (int mi = 0; mi < 4; ++mi) {
        #pragma unroll
        for (int ni = 0; ni < 4; ++ni) {
            int col = n0 + wn + ni * 16 + rr;
            #pragma unroll
            for (int r = 0; r < 4; ++r) {
                int row = m0 + wm + mi * 16 + quad * 4 + r;
                if (row < M) C[(size_t)row * Nn + col] = f2bf(acc[mi][ni][r]);
            }
        }
    }

    // ---- fused attention dots (per covered head) ----
    float ats[4], atd[4];
    #pragma unroll
    for (int ni = 0; ni < 4; ++ni) {
        int cc = wn + ni * 16;                  // col within block tile
        int h = head_base + (cc >> 7);
        int c = (cc + rr) & 127;                // channel within head
        ats[ni] = att_src[h * 128 + c];
        atd[ni] = att_dst[h * 128 + c];
    }
    const int wg = wn >> 6;                     // wave column group
    #pragma unroll
    for (int mi = 0; mi < 4; ++mi) {
        #pragma unroll
        for (int r = 0; r < 4; ++r) {
            float ps = 0.f, pd = 0.f;
            #pragma unroll
            for (int ni = 0; ni < 4; ++ni) {
                ps += ats[ni] * acc[mi][ni][r];
                pd += atd[ni] * acc[mi][ni][r];
            }
            #pragma unroll
            for (int off = 1; off < 16; off <<= 1) {
                ps += __shfl_xor(ps, off, 64);
                pd += __shfl_xor(pd, off, 64);
            }
            if (rr == 0) {
                int row = wm + mi * 16 + quad * 4 + r;   // local row
                psum[wg][row] = ps;
                pdsum[wg][row] = pd;
            }
        }
    }
    __syncthreads();
    if (tid < NH * TM) {
        int h = tid / TM, r = tid % TM;
        int gr = m0 + r;
        if (gr < M) {
            a_srcO[(size_t)gr * H + head_base + h] = psum[2 * h][r] + psum[2 * h + 1][r];
            a_dstO[(size_t)gr * H + head_base + h] = pdsum[2 * h][r] + pdsum[2 * h + 1][r];
        }
    }
}

// ---------------- per-dst-node softmax + aggregation ----------------
// One WAVE per dst node. Single pass: exp(e) without max subtraction (logits
// O(1): identical ratio, fp32-safe). Per-edge scalar-broadcast index loads
// (R12's shfl/bpermute broadcast REVERTED - it regressed). Pipeline depth 4
// for F=512 (4KB/edge in flight), 8 for F=128 (256B/edge, latency-bound).
// No LDS/barriers. Edge order sequential -> deterministic sums.

template<int F, int H, bool RELU, bool BF16OUT>
__global__ __launch_bounds__(256)
void agg_kernel(const unsigned* __restrict__ hfeat, const float* __restrict__ a_src,
                const float* __restrict__ a_dst, const int* __restrict__ row_ptr,
                const int* __restrict__ csr_src, const float* __restrict__ bias,
                void* __restrict__ out_v, int N) {
    constexpr int UPL = F / 128;             // uints per lane: 4 or 1
    constexpr int RU = F / 2;                // uints per row
    constexpr int DEPTH = (UPL == 1) ? 8 : 4;
    const int wave = threadIdx.x >> 6, lane = threadIdx.x & 63;
    const int n = blockIdx.x * 4 + wave;
    if (n >= N) return;
    const int begin = __builtin_amdgcn_readfirstlane(row_ptr[n]);
    const int deg = __builtin_amdgcn_readfirstlane(row_ptr[n + 1]) - begin;
    const int myh = (2 * UPL * lane) / 128;
    const float adst = a_dst[n * H + myh];

    float acc[2 * UPL];
    #pragma unroll
    for (int j = 0; j < 2 * UPL; ++j) acc[j] = 0.f;
    float dacc = 0.f;

    unsigned u[DEPTH][UPL];
    float av[DEPTH];

#define LOAD(d, idx)                                                        \
    {                                                                       \
        int s_ = __builtin_amdgcn_readfirstlane(csr_src[begin + (idx)]);    \
        if (UPL == 4) {                                                     \
            uint4 t_ = ((const uint4*)(hfeat + (size_t)s_ * RU))[lane];     \
            u[d][0] = t_.x; u[d][1] = t_.y; u[d][2] = t_.z; u[d][3] = t_.w; \
        } else {                                                            \
            u[d][0] = hfeat[(size_t)s_ * RU + lane];                        \
        }                                                                   \
        av[d] = a_src[s_ * H + myh];                                        \
    }

#define CONSUME(d)                                                          \
    {                                                                       \
        float e_ = av[d] + adst;                                            \
        e_ = e_ > 0.f ? e_ : NEG_SLOPE * e_;                                \
        float ex_ = __expf(e_);                                             \
        dacc += ex_;                                                        \
        _Pragma("unroll")                                                   \
        for (int q_ = 0; q_ < UPL; ++q_) {                                  \
            acc[2 * q_]     += ex_ * bf2f_lo(u[d][q_]);                     \
            acc[2 * q_ + 1] += ex_ * bf2f_hi(u[d][q_]);                     \
        }                                                                   \
    }

    // fill pipeline
    #pragma unroll
    for (int d = 0; d < DEPTH; ++d)
        if (d < deg) LOAD(d, d);
    // steady state
    int i = 0;
    for (; i + 2 * DEPTH <= deg; i += DEPTH) {
        #pragma unroll
        for (int d = 0; d < DEPTH; ++d) { CONSUME(d); LOAD(d, i + DEPTH + d); }
    }
    // tail: r in [1, 2*DEPTH)
    const int r = deg - i;
    #pragma unroll
    for (int d = 0; d < DEPTH; ++d) {
        if (d < r) {
            CONSUME(d);
            if (d + DEPTH < r) LOAD(d, i + DEPTH + d);
        }
    }
    #pragma unroll
    for (int d = 0; d < DEPTH; ++d)
        if (d + DEPTH < r) CONSUME(d);
#undef LOAD
#undef CONSUME

    // epilogue: lane owns channels [2*UPL*lane, 2*UPL*lane + 2*UPL)
    float inv = 1.f / dacc;
    const int cb = 2 * UPL * lane;
    if (BF16OUT) {
        unsigned pk[UPL];
        #pragma unroll
        for (int q = 0; q < UPL; ++q) {
            float v0 = acc[2 * q] * inv + bias[cb + 2 * q];
            float v1 = acc[2 * q + 1] * inv + bias[cb + 2 * q + 1];
            if (RELU) { v0 = fmaxf(v0, 0.f); v1 = fmaxf(v1, 0.f); }
            pk[q] = (unsigned)f2bf(v0) | ((unsigned)f2bf(v1) << 16);
        }
        if (UPL == 4) {
            uint4 t; t.x = pk[0]; t.y = pk[1]; t.z = pk[2]; t.w = pk[3];
            ((uint4*)((unsigned*)out_v + (size_t)n * RU))[lane] = t;
        } else {
            ((unsigned*)out_v)[(size_t)n * RU + lane] = pk[0];
        }
    } else {
        #pragma unroll
        for (int q = 0; q < UPL; ++q) {
            float v0 = acc[2 * q] * inv + bias[cb + 2 * q];
            float v1 = acc[2 * q + 1] * inv + bias[cb + 2 * q + 1];
            if (RELU) { v0 = fmaxf(v0, 0.f); v1 = fmaxf(v1, 0.f); }
            float2 o; o.x = v0; o.y = v1;
            ((float2*)((float*)out_v + (size_t)n * F))[UPL * lane + q] = o;
        }
    }
}

// ---------------- host launch ----------------

extern "C" void kernel_launch(void* const* d_in, const int* in_sizes, int n_in,
                              void* d_out, int out_size, void* d_ws, size_t ws_size,
                              hipStream_t stream) {
    const float* x        = (const float*)d_in[0];
    const int*   ei       = (const int*)  d_in[1];
    const float* W1       = (const float*)d_in[2];
    const float* att_src1 = (const float*)d_in[3];
    const float* att_dst1 = (const float*)d_in[4];
    const float* b1       = (const float*)d_in[5];
    const float* W2       = (const float*)d_in[6];
    const float* att_src2 = (const float*)d_in[7];
    const float* att_dst2 = (const float*)d_in[8];
    const float* b2       = (const float*)d_in[9];
    const float* W3       = (const float*)d_in[10];
    const float* att_src3 = (const float*)d_in[11];
    const float* att_dst3 = (const float*)d_in[12];
    const float* b3       = (const float*)d_in[13];

    const int IN_FEATS = 256;
    const int N = in_sizes[0] / IN_FEATS;   // 30000
    const int E = in_sizes[1] / 2;          // 480000
    const int ET = E + N;
    const int NB = (N + 1023) / 1024;       // scan blocks (30)

    // workspace layout
    char* p = (char*)d_ws;
    unsigned short* h_bf    = (unsigned short*)p; p += (size_t)N * 512 * sizeof(unsigned short);
    unsigned short* act_bf  = (unsigned short*)p; p += (size_t)N * 512 * sizeof(unsigned short);
    unsigned short* x_bf    = (unsigned short*)p; p += (size_t)N * 256 * sizeof(unsigned short);
    float*          a_src   = (float*)p;          p += (size_t)N * 4 * sizeof(float);
    float*          a_dst   = (float*)p;          p += (size_t)N * 4 * sizeof(float);
    unsigned short* W1T     = (unsigned short*)p; p += (size_t)512 * 256 * sizeof(unsigned short);
    unsigned short* W2T     = (unsigned short*)p; p += (size_t)512 * 512 * sizeof(unsigned short);
    unsigned short* W3T     = (unsigned short*)p; p += (size_t)128 * 512 * sizeof(unsigned short);
    int*            row_ptr = (int*)p;            p += ((size_t)N + 16) * sizeof(int);
    int*            cursor  = (int*)p;            p += ((size_t)N + 16) * sizeof(int);
    int*            bsum    = (int*)p;            p += 64 * sizeof(int);
    int*            csr_src = (int*)p;            p += (size_t)ET * sizeof(int);

    // ---- prep (x cast + W transposes + hist) + CSR build ----
    hipMemsetAsync(cursor, 0, (size_t)N * sizeof(int), stream);
    {
        int n4 = N * 256 / 4;
        int total = n4 + 256 * 512 + 512 * 512 + 512 * 128 + E;
        prep_hist_kernel<<<(total + 255) / 256, 256, 0, stream>>>(
            x, x_bf, W1, W1T, W2, W2T, W3, W3T, ei, cursor, n4, E);
    }
    scan_bsum_kernel<<<NB, 1024, 0, stream>>>(cursor, bsum, N);
    scan_final_kernel<<<NB, 1024, 0, stream>>>(cursor, bsum, row_ptr, N, NB);
    scatter_kernel<<<(E + N + 255) / 256, 256, 0, stream>>>(ei, cursor, csr_src, E, N);

    const int MB128 = (N + 127) / 128;      // 235
    const int MB256 = (N + 255) / 256;      // 118
    const int NB4 = (N + 3) / 4;

    // ---- Layer 1: 256 -> 4x128 concat + relu (h bf16) ----
    mfma_gemm_kernel<128, 256><<<dim3(2, MB128), 512, 0, stream>>>(x_bf, W1T, h_bf, att_src1, att_dst1, a_src, a_dst, 4, N, 512, 256);
    agg_kernel<512, 4, true, true><<<NB4, 256, 0, stream>>>((const unsigned*)h_bf, a_src, a_dst, row_ptr, csr_src, b1, act_bf, N);

    // ---- Layer 2: 512 -> 4x128 concat + relu (h bf16) ----
    mfma_gemm_kernel<128, 256><<<dim3(2, MB128), 512, 0, stream>>>(act_bf, W2T, h_bf, att_src2, att_dst2, a_src, a_dst, 4, N, 512, 512);
    agg_kernel<512, 4, true, true><<<NB4, 256, 0, stream>>>((const unsigned*)h_bf, a_src, a_dst, row_ptr, csr_src, b2, act_bf, N);

    // ---- Layer 3: 512 -> 1x128 (h bf16), fp32 out, no relu ----
    mfma_gemm_kernel<256, 128><<<dim3(1, MB256), 512, 0, stream>>>(act_bf, W3T, h_bf, att_src3, att_dst3, a_src, a_dst, 1, N, 128, 512);
    agg_kernel<128, 1, false, false><<<NB4, 256, 0, stream>>>((const unsigned*)h_bf, a_src, a_dst, row_ptr, csr_src, b3, d_out, N);
}